// Round 1
// baseline (753.877 us; speedup 1.0000x reference)
//
#include <hip/hip_runtime.h>

// GroupedKAAttention on MI355X (gfx950).
// Pipeline: grouped fc1 -> grouped fc4 -> global fc1 (split-K, permuted W rows
// folds the stack/interleave) -> reduce+silu -> global fc4 (split-K) ->
// reduce+silu -> per-row dot -> softmax over batch.
// All GEMMs: bf16x3 split (hi/lo) MFMA 16x16x32, fp32 accumulate; 128x128 tile,
// BK=32, 4 waves, XOR-swizzled LDS (2-way conflict-free b128 frag reads),
// reg-staged global->LDS with fp32->bf16 hi/lo conversion, next-tile prefetch.

#define CB 256      // batch
#define CG 16       // groups
#define CGS 588     // group size
#define CHID 1024
#define CFEAT 2048

typedef __attribute__((ext_vector_type(8))) short bf16x8;
typedef __attribute__((ext_vector_type(4))) float f32x4;

__device__ __forceinline__ int lds_addr(int row, int kcol) {
  // 128 rows x 32 bf16 (64B) per plane; swizzle 16B slot by (row>>1)&3 so that
  // b128 frag reads (16 rows, same k-block) spread over 8 slots -> 2-way free.
  return row * 64 + ((((kcol >> 3) ^ ((row >> 1) & 3)) << 4) | ((kcol & 7) << 1));
}

__device__ __forceinline__ void split4(const float4& v, uint2& hi, uint2& lo) {
  // x = hi + lo, both bf16 (truncation split: |x-(hi+lo)| <= 2^-16 |x|)
  unsigned u0 = __float_as_uint(v.x), u1 = __float_as_uint(v.y);
  unsigned u2 = __float_as_uint(v.z), u3 = __float_as_uint(v.w);
  unsigned h0 = u0 & 0xffff0000u, h1 = u1 & 0xffff0000u;
  unsigned h2 = u2 & 0xffff0000u, h3 = u3 & 0xffff0000u;
  hi.x = (h0 >> 16) | h1;
  hi.y = (h2 >> 16) | h3;
  float r0 = v.x - __uint_as_float(h0), r1 = v.y - __uint_as_float(h1);
  float r2 = v.z - __uint_as_float(h2), r3 = v.w - __uint_as_float(h3);
  lo.x = (__float_as_uint(r0) >> 16) | (__float_as_uint(r1) & 0xffff0000u);
  lo.y = (__float_as_uint(r2) >> 16) | (__float_as_uint(r3) & 0xffff0000u);
}

__device__ __forceinline__ float silu_f(float x) {
  return x / (1.f + __expf(-x));
}

// ---------------------------------------------------------------------------
// Generic 128x128 tile GEMM, C = silu(A*B + bias) or raw partial (split-K).
// GROUPED: blockIdx.z = br*16+g selects branch (q/k) and group.
// PERMUTE: B row index = ((k&2047)<<4)|(k>>11)  (stack-interleave folded in).
// EPILOGUE: bias+silu store; else raw fp32 partial store (ldc = N).
// ---------------------------------------------------------------------------
template <int GROUPED, int PERMUTE, int EPILOGUE>
__global__ __launch_bounds__(256, 2) void gemm_k(
    const float* __restrict__ A0, const float* __restrict__ A1,
    const float* __restrict__ B0, const float* __restrict__ B1,
    const float* __restrict__ bias0, const float* __restrict__ bias1,
    float* __restrict__ C, int K, int lda, int ldb, int ldc, int a_goff,
    long a_broff, long b_gstride, int bias_gstride, long c_broff, int c_goff,
    long c_sstride, int nksteps) {
  __shared__ __align__(16) char sm[32768];
  constexpr int A_HI = 0, A_LO = 8192, B_HI = 16384, B_LO = 24576;
  const int tid = threadIdx.x;
  const int m0 = blockIdx.x * 128, n0 = blockIdx.y * 128;

  const float* Ap;
  const float* Bp;
  const float* bp = nullptr;
  float* Cb;
  int acol = 0;
  int kbase = 0;
  if (GROUPED) {
    int z = blockIdx.z;
    int br = z >> 4, g = z & 15;
    Ap = (br ? A1 : A0) + (long)br * a_broff;
    Bp = (br ? B1 : B0) + (long)g * b_gstride;
    if (EPILOGUE) bp = (br ? bias1 : bias0) + (long)g * bias_gstride;
    Cb = C + (long)br * c_broff + (long)g * c_goff;
    acol = g * a_goff;
  } else {
    Ap = A0;
    Bp = B0;
    bp = bias0;
    Cb = C + (long)blockIdx.z * c_sstride;
    kbase = (int)blockIdx.z * nksteps * 32;
  }

  float4 ga[4];      // A tile regs: 4 rows x 4 k each
  float gb[4][4];    // B tile regs: 4 passes x 4 k each (one n)

  auto tload = [&](int k0) {
    const int r = tid >> 3, c4 = (tid & 7) << 2;
    const int gk = k0 + c4;
    #pragma unroll
    for (int i = 0; i < 4; ++i) {
      if (gk < K)
        ga[i] = *reinterpret_cast<const float4*>(Ap + (long)(m0 + i * 32 + r) * lda + acol + gk);
      else
        ga[i] = make_float4(0.f, 0.f, 0.f, 0.f);
    }
    const int n = tid & 127, kq0 = (tid >> 7) << 2;
    #pragma unroll
    for (int i = 0; i < 4; ++i) {
      #pragma unroll
      for (int j = 0; j < 4; ++j) {
        int kk = k0 + i * 8 + kq0 + j;
        float v = 0.f;
        if (kk < K) {
          long brow = PERMUTE ? (long)(((kk & 2047) << 4) | (kk >> 11)) : (long)kk;
          v = Bp[brow * ldb + n0 + n];
        }
        gb[i][j] = v;
      }
    }
  };

  auto tstore = [&]() {
    const int r = tid >> 3, c4 = (tid & 7) << 2;
    #pragma unroll
    for (int i = 0; i < 4; ++i) {
      uint2 h, l;
      split4(ga[i], h, l);
      int ad = lds_addr(i * 32 + r, c4);
      *reinterpret_cast<uint2*>(sm + A_HI + ad) = h;
      *reinterpret_cast<uint2*>(sm + A_LO + ad) = l;
    }
    const int n = tid & 127, kq0 = (tid >> 7) << 2;
    #pragma unroll
    for (int i = 0; i < 4; ++i) {
      float4 v = make_float4(gb[i][0], gb[i][1], gb[i][2], gb[i][3]);
      uint2 h, l;
      split4(v, h, l);
      int ad = lds_addr(n, i * 8 + kq0);
      *reinterpret_cast<uint2*>(sm + B_HI + ad) = h;
      *reinterpret_cast<uint2*>(sm + B_LO + ad) = l;
    }
  };

  f32x4 acc[4][4];
  #pragma unroll
  for (int a = 0; a < 4; ++a)
    #pragma unroll
    for (int b = 0; b < 4; ++b) acc[a][b] = (f32x4){0.f, 0.f, 0.f, 0.f};

  const int lane = tid & 63, w = tid >> 6;
  const int wr = w >> 1, wc = w & 1;
  const int fr = lane & 15, kb = lane >> 4;

  tload(kbase);
  for (int s = 0; s < nksteps; ++s) {
    tstore();
    __syncthreads();
    if (s + 1 < nksteps) tload(kbase + (s + 1) * 32);  // prefetch under MFMA

    bf16x8 ah[4], al[4], bh[4], bl[4];
    #pragma unroll
    for (int f = 0; f < 4; ++f) {
      int row = wr * 64 + f * 16 + fr;
      int ad = row * 64 + ((kb ^ ((row >> 1) & 3)) << 4);
      ah[f] = *reinterpret_cast<const bf16x8*>(sm + A_HI + ad);
      al[f] = *reinterpret_cast<const bf16x8*>(sm + A_LO + ad);
      int rob = wc * 64 + f * 16 + fr;
      int bd = rob * 64 + ((kb ^ ((rob >> 1) & 3)) << 4);
      bh[f] = *reinterpret_cast<const bf16x8*>(sm + B_HI + bd);
      bl[f] = *reinterpret_cast<const bf16x8*>(sm + B_LO + bd);
    }
    #pragma unroll
    for (int im = 0; im < 4; ++im) {
      #pragma unroll
      for (int jn = 0; jn < 4; ++jn) {
        acc[im][jn] = __builtin_amdgcn_mfma_f32_16x16x32_bf16(ah[im], bh[jn], acc[im][jn], 0, 0, 0);
        acc[im][jn] = __builtin_amdgcn_mfma_f32_16x16x32_bf16(ah[im], bl[jn], acc[im][jn], 0, 0, 0);
        acc[im][jn] = __builtin_amdgcn_mfma_f32_16x16x32_bf16(al[im], bh[jn], acc[im][jn], 0, 0, 0);
      }
    }
    __syncthreads();
  }

  // Epilogue. C/D frag layout: col = lane&15, row = (lane>>4)*4 + reg  [m89]
  #pragma unroll
  for (int jn = 0; jn < 4; ++jn) {
    int col = n0 + wc * 64 + jn * 16 + fr;
    float bv = EPILOGUE ? bp[col] : 0.f;
    #pragma unroll
    for (int im = 0; im < 4; ++im) {
      int row0 = m0 + wr * 64 + im * 16 + kb * 4;
      #pragma unroll
      for (int j = 0; j < 4; ++j) {
        float x = acc[im][jn][j];
        if (EPILOGUE)
          Cb[(long)(row0 + j) * ldc + col] = silu_f(x + bv);
        else
          Cb[(long)(row0 + j) * ldc + col] = x;
      }
    }
  }
}

// Sum split-K partials, add bias, silu.
__global__ __launch_bounds__(256) void reduce_silu_k(
    const float* __restrict__ part, const float* __restrict__ bias,
    float* __restrict__ out, long MN, int N, int S) {
  long idx = ((long)blockIdx.x * blockDim.x + threadIdx.x) * 4;
  long stride = (long)gridDim.x * blockDim.x * 4;
  for (; idx < MN; idx += stride) {
    float4 a = make_float4(0.f, 0.f, 0.f, 0.f);
    for (int s = 0; s < S; ++s) {
      float4 p = *reinterpret_cast<const float4*>(&part[(long)s * MN + idx]);
      a.x += p.x; a.y += p.y; a.z += p.z; a.w += p.w;
    }
    int col = (int)(idx & (N - 1));
    float4 b = *reinterpret_cast<const float4*>(&bias[col]);
    float4 o;
    o.x = silu_f(a.x + b.x);
    o.y = silu_f(a.y + b.y);
    o.z = silu_f(a.z + b.z);
    o.w = silu_f(a.w + b.w);
    *reinterpret_cast<float4*>(&out[idx]) = o;
  }
}

// scores[b] = dot(q_out[b], k_out[b]); out2 = [512][2048], rows 0-255 q, 256-511 k.
__global__ __launch_bounds__(256) void scores_k(const float* __restrict__ out2,
                                                float* __restrict__ scores) {
  int b = blockIdx.x;
  const float* qo = out2 + (long)b * CFEAT;
  const float* ko = out2 + (long)(b + CB) * CFEAT;
  float s = 0.f;
  for (int i = threadIdx.x * 4; i < CFEAT; i += 1024) {
    float4 a = *reinterpret_cast<const float4*>(&qo[i]);
    float4 c = *reinterpret_cast<const float4*>(&ko[i]);
    s += a.x * c.x + a.y * c.y + a.z * c.z + a.w * c.w;
  }
  #pragma unroll
  for (int o = 32; o; o >>= 1) s += __shfl_down(s, o, 64);
  __shared__ float red[4];
  if ((threadIdx.x & 63) == 0) red[threadIdx.x >> 6] = s;
  __syncthreads();
  if (threadIdx.x == 0) scores[b] = red[0] + red[1] + red[2] + red[3];
}

// softmax over the 256 batch entries (one block).
__global__ __launch_bounds__(256) void softmax_k(const float* __restrict__ scores,
                                                 float* __restrict__ out) {
  int t = threadIdx.x;
  float v = scores[t];
  float m = v;
  #pragma unroll
  for (int o = 32; o; o >>= 1) m = fmaxf(m, __shfl_xor(m, o, 64));
  __shared__ float redm[4];
  if ((t & 63) == 0) redm[t >> 6] = m;
  __syncthreads();
  m = fmaxf(fmaxf(redm[0], redm[1]), fmaxf(redm[2], redm[3]));
  float e = __expf(v - m);
  float s = e;
  #pragma unroll
  for (int o = 32; o; o >>= 1) s += __shfl_xor(s, o, 64);
  __shared__ float reds[4];
  if ((t & 63) == 0) reds[t >> 6] = s;
  __syncthreads();
  s = reds[0] + reds[1] + reds[2] + reds[3];
  out[t] = e / s;
}

extern "C" void kernel_launch(void* const* d_in, const int* in_sizes, int n_in,
                              void* d_out, int out_size, void* d_ws,
                              size_t ws_size, hipStream_t stream) {
  const float* q   = (const float*)d_in[0];
  const float* kx  = (const float*)d_in[1];
  const float* Wq1 = (const float*)d_in[2];
  const float* bq1 = (const float*)d_in[3];
  const float* Wq4 = (const float*)d_in[4];
  const float* bq4 = (const float*)d_in[5];
  const float* Wk1 = (const float*)d_in[6];
  const float* bk1 = (const float*)d_in[7];
  const float* Wk4 = (const float*)d_in[8];
  const float* bk4 = (const float*)d_in[9];
  const float* Wg1 = (const float*)d_in[10];
  const float* bg1 = (const float*)d_in[11];
  const float* Wg4 = (const float*)d_in[12];
  const float* bg4 = (const float*)d_in[13];
  float* out = (float*)d_out;
  char* ws = (char*)d_ws;

  // ws layout (bytes), with time-disjoint reuse; peak = 100,663,296 B:
  float* hqk   = (float*)(ws);                        // [2][256][16][1024] 33.5MB
  float* fqk   = (float*)(ws + 33554432);             // [2][256][16][2048] 67.1MB
  float* part3 = (float*)(ws);                        // [8][512][1024] 16.8MB (hqk dead)
  float* h2    = (float*)(ws + 16777216);             // [512][1024] 2MB
  float* scors = (float*)(ws + 18874368);             // [256]
  float* part4 = (float*)(ws + 33554432);             // [4][512][2048] 16.8MB (fqk dead)
  float* out2  = (float*)(ws + 50331648);             // [512][2048] 4MB

  dim3 blk(256);

  // 1) grouped fc1: 16x [256x588]x[588x1024] (+bias, silu), both branches
  gemm_k<1, 0, 1><<<dim3(2, 8, 32), blk, 0, stream>>>(
      q, kx, Wq1, Wk1, bq1, bk1, hqk, /*K*/ CGS, /*lda*/ CG * CGS,
      /*ldb*/ CHID, /*ldc*/ CG * CHID, /*a_goff*/ CGS, /*a_broff*/ 0L,
      /*b_gstride*/ (long)CGS * CHID, /*bias_g*/ CHID,
      /*c_broff*/ (long)CB * CG * CHID, /*c_goff*/ CHID, 0L, /*nk*/ 19);

  // 2) grouped fc4: 16x [256x1024]x[1024x2048] (+bias, silu)
  gemm_k<1, 0, 1><<<dim3(2, 16, 32), blk, 0, stream>>>(
      hqk, hqk, Wq4, Wk4, bq4, bk4, fqk, /*K*/ CHID, /*lda*/ CG * CHID,
      /*ldb*/ CFEAT, /*ldc*/ CG * CFEAT, /*a_goff*/ CHID,
      /*a_broff*/ (long)CB * CG * CHID, /*b_gstride*/ (long)CHID * CFEAT,
      /*bias_g*/ CFEAT, /*c_broff*/ (long)CB * CG * CFEAT, /*c_goff*/ CFEAT, 0L,
      /*nk*/ 32);

  // 3) global fc1: [512x32768]x[32768x1024], split-K=8, permuted W rows
  gemm_k<0, 1, 0><<<dim3(4, 8, 8), blk, 0, stream>>>(
      fqk, fqk, Wg1, Wg1, bg1, bg1, part3, /*K*/ CG * CFEAT, /*lda*/ CG * CFEAT,
      /*ldb*/ CHID, /*ldc*/ CHID, 0, 0L, 0L, 0, 0L, 0,
      /*c_sstride*/ (long)512 * CHID, /*nk*/ 128);
  reduce_silu_k<<<512, blk, 0, stream>>>(part3, bg1, h2, (long)512 * CHID, CHID, 8);

  // 4) global fc4: [512x1024]x[1024x2048], split-K=4
  gemm_k<0, 0, 0><<<dim3(4, 16, 4), blk, 0, stream>>>(
      h2, h2, Wg4, Wg4, bg4, bg4, part4, /*K*/ CHID, /*lda*/ CHID,
      /*ldb*/ CFEAT, /*ldc*/ CFEAT, 0, 0L, 0L, 0, 0L, 0,
      /*c_sstride*/ (long)512 * CFEAT, /*nk*/ 8);
  reduce_silu_k<<<1024, blk, 0, stream>>>(part4, bg4, out2, (long)512 * CFEAT, CFEAT, 4);

  // 5) scores + softmax over batch
  scores_k<<<256, blk, 0, stream>>>(out2, scors);
  softmax_k<<<1, blk, 0, stream>>>(scors, out);
}